// Round 10
// baseline (392.131 us; speedup 1.0000x reference)
//
#include <hip/hip_runtime.h>

#define HWN    262144
#define KSEL   65536
#define TIECAP 2048

// ---- small-region byte offsets in d_ws
#define OFF_H      0          // double[64*64]   h (post LN1+relu), row-major
#define OFF_DOT1   32768      // double[64*64]   reduced GEMM1
#define OFF_G      65536      // double[64*64]   W2^T W2
#define OFF_WBAR   98304      // double[64]      col sums of W2
#define OFF_WB     98816      // double[64]      sum W2[:,k]*b2
#define OFF_SB     99328      // double[2]       {sum b2, sum b2^2}
#define OFF_MU2    99360      // double[64]
#define OFF_ISIG2  99872      // double[64]
#define OFF_STATE  100384     // u32[4][4] {prefix, need, T, needT}
#define OFF_HIST   100448     // u32[4 passes][4][256]
#define OFF_TIECNT 116832     // u32[4]
#define OFF_CHCNT  116848     // u32[4]
#define OFF_TIELST 116864     // u32[4][TIECAP]
#define OFF_CHLST  149632     // u32[4][TIECAP]
#define OFF_BCNT   182400     // u32[4][256]
#define OFF_BOFF   186496     // u32[4][256]
#define OFF_BNP    190592     // double[1024][16][2]
#define OFF_BNC    452736     // float[16][2]
#define OFF_PART2  458752     // double[16][4226] stage-1 reduction output (540928 B)
#define OFF_HT     1015808    // double[64 k][64 row] h transposed (32768 B)
#define REGION2    1048576    // big region: partG|partD, later score/key/gbuf

#define PS_GRAM 4226          // [64][66] + {sb2, sb}
#define PS_DOT  4096          // [64][64]

typedef double d4_t __attribute__((ext_vector_type(4)));
typedef float  f4v  __attribute__((ext_vector_type(4)));

__device__ __forceinline__ unsigned monokey(double s){
  unsigned long long b = (unsigned long long)__double_as_longlong(s);
  b = (b & 0x8000000000000000ULL) ? ~b : (b | 0x8000000000000000ULL);
  return (unsigned)(b >> 32);
}

// ------------------------------------------------------------------ zero/init
__global__ void k_zero(unsigned* hist, unsigned* tiecnt, unsigned* chcnt, unsigned* state){
  int t = threadIdx.x;
  for (int i = t; i < 4096; i += 256) hist[i] = 0u;
  if (t < 4){
    tiecnt[t] = 0u; chcnt[t] = 0u;
    state[t*4+0] = 0u;          // prefix
    state[t*4+1] = (unsigned)KSEL; // need
    state[t*4+2] = 0u;          // T
    state[t*4+3] = 0u;          // needT
  }
}

// store one 16x16 MFMA tile (ai,bi) of the symmetric-gram layout.
// bi<4: full G tile; bi==4,ai<4: wb/wbar cols; ai==4: sb2/sb scalars.
__device__ __forceinline__ void st_tile(double* __restrict__ P, const d4_t& acc,
                                        const int* ri_, const int* ci_, int ai, int bi){
#pragma unroll
  for (int i = 0; i < 4; i++){
    int ri = ri_[i], ci = ci_[i];
    if (bi < 4)            P[(ai*16+ri)*66 + bi*16 + ci] = acc[i];
    else if (ai < 4){ if (ci < 2) P[(ai*16+ri)*66 + 64 + ci] = acc[i]; }
    else { if (ri == 0 && ci < 2) P[4224 + ci] = acc[i]; }  // [0][0]=sb2,[0][1]=sb
  }
}

// ---------------- fused fp64-MFMA GEMMs: gram(W2) on blocks [0,NBH), GEMM1 on
// [NBH,2NBH).  Probe-store (verified R6) decodes the HW D-fragment (row,col).
// R10: gram exploits G=G^T — 15 tiles (upper triangle + aux) spread 4/4/4/3
// across waves instead of 21; k_mm is at the f64-MFMA pipe ceiling (~40cyc/CU
// fitted R7-R9), so instruction-count reduction is the remaining lever.
__global__ __launch_bounds__(256) void k_mm(const float* __restrict__ W2,
                                            const float* __restrict__ b2,
                                            const float* __restrict__ inp,
                                            const float* __restrict__ W1,
                                            double* __restrict__ partG,
                                            double* __restrict__ partD,
                                            int pPerBlk, int NBH){
  int t = threadIdx.x;
  int w = t >> 6, l = t & 63;
  int q = l >> 4, m = l & 15;
  if ((int)blockIdx.x < NBH){
    // ---------------- gram path: Atilde = [W2 | b2 | 1], upper-tri tiles only
    int p0 = blockIdx.x * pPerBlk;
    d4_t accA = {0.,0.,0.,0.}, accB = {0.,0.,0.,0.};
    d4_t accC = {0.,0.,0.,0.}, accD = {0.,0.,0.,0.};
    const float* base = W2 + (size_t)(p0 + q)*64 + m;
    const float* b2p  = b2 + p0 + q;
    int nCh = pPerBlk >> 2;
    float g0 = base[0], g1 = base[16], g2 = base[32], g3 = base[48], gb = b2p[0];
    for (int c = 0; c < nCh-1; c++){
      base += 256; b2p += 4;
      float n0 = base[0], n1 = base[16], n2 = base[32], n3 = base[48], nb = b2p[0];
      double f0 = (double)g0, f1 = (double)g1, f2 = (double)g2, f3 = (double)g3;
      double f4 = (m == 0) ? (double)gb : ((m == 1) ? 1.0 : 0.0);
      if (w == 0){
        accA = __builtin_amdgcn_mfma_f64_16x16x4f64(f0, f0, accA, 0, 0, 0);
        accB = __builtin_amdgcn_mfma_f64_16x16x4f64(f0, f1, accB, 0, 0, 0);
        accC = __builtin_amdgcn_mfma_f64_16x16x4f64(f0, f2, accC, 0, 0, 0);
        accD = __builtin_amdgcn_mfma_f64_16x16x4f64(f0, f3, accD, 0, 0, 0);
      } else if (w == 1){
        accA = __builtin_amdgcn_mfma_f64_16x16x4f64(f1, f1, accA, 0, 0, 0);
        accB = __builtin_amdgcn_mfma_f64_16x16x4f64(f1, f2, accB, 0, 0, 0);
        accC = __builtin_amdgcn_mfma_f64_16x16x4f64(f1, f3, accC, 0, 0, 0);
        accD = __builtin_amdgcn_mfma_f64_16x16x4f64(f1, f4, accD, 0, 0, 0);
      } else if (w == 2){
        accA = __builtin_amdgcn_mfma_f64_16x16x4f64(f2, f2, accA, 0, 0, 0);
        accB = __builtin_amdgcn_mfma_f64_16x16x4f64(f2, f3, accB, 0, 0, 0);
        accC = __builtin_amdgcn_mfma_f64_16x16x4f64(f2, f4, accC, 0, 0, 0);
        accD = __builtin_amdgcn_mfma_f64_16x16x4f64(f3, f4, accD, 0, 0, 0);
      } else {
        accA = __builtin_amdgcn_mfma_f64_16x16x4f64(f3, f3, accA, 0, 0, 0);
        accB = __builtin_amdgcn_mfma_f64_16x16x4f64(f0, f4, accB, 0, 0, 0);
        accC = __builtin_amdgcn_mfma_f64_16x16x4f64(f4, f4, accC, 0, 0, 0);
      }
      g0 = n0; g1 = n1; g2 = n2; g3 = n3; gb = nb;
    }
    { // peeled last chunk
      double f0 = (double)g0, f1 = (double)g1, f2 = (double)g2, f3 = (double)g3;
      double f4 = (m == 0) ? (double)gb : ((m == 1) ? 1.0 : 0.0);
      if (w == 0){
        accA = __builtin_amdgcn_mfma_f64_16x16x4f64(f0, f0, accA, 0, 0, 0);
        accB = __builtin_amdgcn_mfma_f64_16x16x4f64(f0, f1, accB, 0, 0, 0);
        accC = __builtin_amdgcn_mfma_f64_16x16x4f64(f0, f2, accC, 0, 0, 0);
        accD = __builtin_amdgcn_mfma_f64_16x16x4f64(f0, f3, accD, 0, 0, 0);
      } else if (w == 1){
        accA = __builtin_amdgcn_mfma_f64_16x16x4f64(f1, f1, accA, 0, 0, 0);
        accB = __builtin_amdgcn_mfma_f64_16x16x4f64(f1, f2, accB, 0, 0, 0);
        accC = __builtin_amdgcn_mfma_f64_16x16x4f64(f1, f3, accC, 0, 0, 0);
        accD = __builtin_amdgcn_mfma_f64_16x16x4f64(f1, f4, accD, 0, 0, 0);
      } else if (w == 2){
        accA = __builtin_amdgcn_mfma_f64_16x16x4f64(f2, f2, accA, 0, 0, 0);
        accB = __builtin_amdgcn_mfma_f64_16x16x4f64(f2, f3, accB, 0, 0, 0);
        accC = __builtin_amdgcn_mfma_f64_16x16x4f64(f2, f4, accC, 0, 0, 0);
        accD = __builtin_amdgcn_mfma_f64_16x16x4f64(f3, f4, accD, 0, 0, 0);
      } else {
        accA = __builtin_amdgcn_mfma_f64_16x16x4f64(f3, f3, accA, 0, 0, 0);
        accB = __builtin_amdgcn_mfma_f64_16x16x4f64(f0, f4, accB, 0, 0, 0);
        accC = __builtin_amdgcn_mfma_f64_16x16x4f64(f4, f4, accC, 0, 0, 0);
      }
    }
    // probes: prD = 4*(1+row), pcD = 4*(1+col) under the HW's true maps
    d4_t prD = {0.,0.,0.,0.}, pcD = {0.,0.,0.,0.};
    double rp = (double)(1 + m);
    prD = __builtin_amdgcn_mfma_f64_16x16x4f64(rp, 1.0, prD, 0, 0, 0);
    pcD = __builtin_amdgcn_mfma_f64_16x16x4f64(1.0, rp, pcD, 0, 0, 0);
    int ri_[4], ci_[4];
#pragma unroll
    for (int i = 0; i < 4; i++){
      ri_[i] = ((((int)prD[i]) >> 2) - 1) & 15;
      ci_[i] = ((((int)pcD[i]) >> 2) - 1) & 15;
    }
    double* P = partG + (size_t)blockIdx.x * PS_GRAM;
    if (w == 0){
      st_tile(P, accA, ri_, ci_, 0, 0); st_tile(P, accB, ri_, ci_, 0, 1);
      st_tile(P, accC, ri_, ci_, 0, 2); st_tile(P, accD, ri_, ci_, 0, 3);
    } else if (w == 1){
      st_tile(P, accA, ri_, ci_, 1, 1); st_tile(P, accB, ri_, ci_, 1, 2);
      st_tile(P, accC, ri_, ci_, 1, 3); st_tile(P, accD, ri_, ci_, 1, 4);
    } else if (w == 2){
      st_tile(P, accA, ri_, ci_, 2, 2); st_tile(P, accB, ri_, ci_, 2, 3);
      st_tile(P, accC, ri_, ci_, 2, 4); st_tile(P, accD, ri_, ci_, 3, 4);
    } else {
      st_tile(P, accA, ri_, ci_, 3, 3); st_tile(P, accB, ri_, ci_, 0, 4);
      st_tile(P, accC, ri_, ci_, 4, 4);
    }
  } else {
    // ---------------- GEMM1 path: dot1[r][k] = sum_p inp[r][p] * W1[k][p]
    int blk = (int)blockIdx.x - NBH;
    int p0 = blk * pPerBlk;
    d4_t acc0 = {0.,0.,0.,0.}, acc1 = {0.,0.,0.,0.};
    d4_t acc2 = {0.,0.,0.,0.}, acc3 = {0.,0.,0.,0.};
    const f4v* ap  = (const f4v*)(inp + (size_t)(w*16 + m)*HWN + p0 + q*4);
    const f4v* bp0 = (const f4v*)(W1  + (size_t)( 0 + m)*HWN + p0 + q*4);
    const f4v* bp1 = (const f4v*)(W1  + (size_t)(16 + m)*HWN + p0 + q*4);
    const f4v* bp2 = (const f4v*)(W1  + (size_t)(32 + m)*HWN + p0 + q*4);
    const f4v* bp3 = (const f4v*)(W1  + (size_t)(48 + m)*HWN + p0 + q*4);
    int nCh = pPerBlk >> 4;
    f4v av = ap[0], b0 = bp0[0], b1 = bp1[0], b2v = bp2[0], b3 = bp3[0];
    for (int c = 0; c < nCh-1; c++){
      size_t nx = (size_t)(c+1)*4;
      f4v avn = ap[nx], b0n = bp0[nx], b1n = bp1[nx], b2n = bp2[nx], b3n = bp3[nx];
#pragma unroll
      for (int t4 = 0; t4 < 4; t4++){
        double a = (double)av[t4];
        acc0 = __builtin_amdgcn_mfma_f64_16x16x4f64(a, (double)b0[t4],  acc0, 0, 0, 0);
        acc1 = __builtin_amdgcn_mfma_f64_16x16x4f64(a, (double)b1[t4],  acc1, 0, 0, 0);
        acc2 = __builtin_amdgcn_mfma_f64_16x16x4f64(a, (double)b2v[t4], acc2, 0, 0, 0);
        acc3 = __builtin_amdgcn_mfma_f64_16x16x4f64(a, (double)b3[t4],  acc3, 0, 0, 0);
      }
      av = avn; b0 = b0n; b1 = b1n; b2v = b2n; b3 = b3n;
    }
#pragma unroll
    for (int t4 = 0; t4 < 4; t4++){  // peeled last chunk
      double a = (double)av[t4];
      acc0 = __builtin_amdgcn_mfma_f64_16x16x4f64(a, (double)b0[t4],  acc0, 0, 0, 0);
      acc1 = __builtin_amdgcn_mfma_f64_16x16x4f64(a, (double)b1[t4],  acc1, 0, 0, 0);
      acc2 = __builtin_amdgcn_mfma_f64_16x16x4f64(a, (double)b2v[t4], acc2, 0, 0, 0);
      acc3 = __builtin_amdgcn_mfma_f64_16x16x4f64(a, (double)b3[t4],  acc3, 0, 0, 0);
    }
    d4_t prD = {0.,0.,0.,0.}, pcD = {0.,0.,0.,0.};
    double rp = (double)(1 + m);
    prD = __builtin_amdgcn_mfma_f64_16x16x4f64(rp, 1.0, prD, 0, 0, 0);
    pcD = __builtin_amdgcn_mfma_f64_16x16x4f64(1.0, rp, pcD, 0, 0, 0);
    double* P = partD + (size_t)blk * PS_DOT;
#pragma unroll
    for (int i = 0; i < 4; i++){
      int ri = ((((int)prD[i]) >> 2) - 1) & 15;
      int ci = ((((int)pcD[i]) >> 2) - 1) & 15;
      int r = w*16 + ri;
      P[r*64 +  0 + ci] = acc0[i];
      P[r*64 + 16 + ci] = acc1[i];
      P[r*64 + 32 + ci] = acc2[i];
      P[r*64 + 48 + ci] = acc3[i];
    }
  }
}

// ------------------------------------------------- two-stage partial reduction
// Stage 1: [NBH][cnt] -> [16][cnt].  Grid = ceil(cnt/256) j-chunks * 16 groups.
__global__ __launch_bounds__(256) void k_red1(const double* __restrict__ part,
                                              double* __restrict__ part2,
                                              int bPerGrp, int cnt){
  int nj = (cnt + 255) >> 8;
  int jc = blockIdx.x % nj;
  int grp = blockIdx.x / nj;
  int j = jc*256 + threadIdx.x;
  if (j >= cnt) return;
  const double* p = part + (size_t)grp * bPerGrp * cnt + j;
  double s0=0.0, s1=0.0, s2=0.0, s3=0.0;
  for (int b = 0; b < bPerGrp; b += 4){
    s0 += p[(size_t)(b+0)*cnt];
    s1 += p[(size_t)(b+1)*cnt];
    s2 += p[(size_t)(b+2)*cnt];
    s3 += p[(size_t)(b+3)*cnt];
  }
  part2[(size_t)grp*cnt + j] = (s0+s1) + (s2+s3);
}

// Stage 2 (gram): [16][4226] -> G/wb/wbar/sbv.  Lower-triangle blocks mirror
// from the transposed stored tile (k_mm writes upper-tri tiles only).
__global__ void k_redgram2(const double* __restrict__ part2,
                           double* __restrict__ G, double* __restrict__ wb,
                           double* __restrict__ wbar, double* __restrict__ sbv){
  int j = blockIdx.x*256 + threadIdx.x;
  if (j >= PS_GRAM) return;
  int src = j;
  int r = 0, c = 0;
  if (j < 4224){
    r = j / 66; c = j % 66;
    if (c < 64){
      int rb = r >> 4, cb = c >> 4;
      if (cb < rb)  // lower block: value lives in tile (cb, rb) transposed
        src = ((cb*16 + (c & 15)) * 66) + rb*16 + (r & 15);
    }
  }
  double s = 0.0;
#pragma unroll
  for (int b = 0; b < 16; b++) s += part2[(size_t)b*PS_GRAM + src];
  if (j < 4224){
    if (c < 64) G[r*64 + c] = s;
    else if (c == 64) wb[r] = s;
    else wbar[r] = s;
  } else if (j == 4224) sbv[1] = s;   // sum b2^2
  else sbv[0] = s;                    // sum b2
}

// Stage 2 (dot1): [16][4096] -> dot1[4096]
__global__ void k_reddot2(const double* __restrict__ part2, double* __restrict__ dot1){
  int j = blockIdx.x*256 + threadIdx.x;
  if (j >= PS_DOT) return;
  double s = 0.0;
#pragma unroll
  for (int b = 0; b < 16; b++) s += part2[(size_t)b*PS_DOT + j];
  dot1[j] = s;
}

// ------------------- LN1 -> h (row-major + transposed), and LN2 mean (analytic)
__global__ void k_h(const double* __restrict__ dot1, const float* __restrict__ b1,
                    const float* __restrict__ g1, const float* __restrict__ b1l,
                    const double* __restrict__ wbar, const double* __restrict__ sbv,
                    double* __restrict__ h, double* __restrict__ hT,
                    double* __restrict__ mu2){
  int r = threadIdx.x; // 0..63
  double m = 0.0;
  for (int k=0;k<64;k++) m += dot1[r*64+k] + (double)b1[k];
  m *= (1.0/64.0);
  double v = 0.0;
  for (int k=0;k<64;k++){ double d = dot1[r*64+k] + (double)b1[k] - m; v += d*d; }
  v *= (1.0/64.0);
  double inv = 1.0 / sqrt(v + 1e-5);
  double s2 = 0.0;
  for (int k=0;k<64;k++){
    double x = dot1[r*64+k] + (double)b1[k];
    double z = (x - m) * inv;
    double hv = z * (double)g1[k] + (double)b1l[k];
    hv = hv > 0.0 ? hv : 0.0;
    h[r*64+k] = hv;
    hT[k*64+r] = hv;
    s2 += hv * wbar[k];
  }
  mu2[r] = (s2 + sbv[0]) / (double)HWN;
}

// -------------------------------------------------- LN2 variance via Gram(W2)
__global__ void k_var2(const double* __restrict__ h, const double* __restrict__ G,
                       const double* __restrict__ wb, const double* __restrict__ sbv,
                       const double* __restrict__ mu2, double* __restrict__ isig2){
  int r = blockIdx.x, k = threadIdx.x;
  double hk = h[r*64+k];
  double v = 0.0;
  for (int l=0;l<64;l++) v += G[k*64+l] * h[r*64+l];
  double contrib = hk*v + 2.0*hk*wb[k];
  for (int o=32;o>0;o>>=1) contrib += __shfl_down(contrib, o);
  if (k == 0){
    double E2 = (contrib + sbv[1]) / (double)HWN;
    double mu = mu2[r];
    double var = E2 - mu*mu;
    isig2[r] = 1.0 / sqrt(var + 1e-5);
  }
}

// ------------------------------------------------ GEMM2 + LN2 + relu + score
// hT rows are wave-uniform -> scalar (s_load) broadcast, no LDS at all.
#define SC_K(WF, KIDX) { \
  double w_ = (double)(WF); \
  const double* hp_ = hb + (KIDX)*64; \
  acc[0]+=hp_[0]*w_;  acc[1]+=hp_[1]*w_;  acc[2]+=hp_[2]*w_;  acc[3]+=hp_[3]*w_; \
  acc[4]+=hp_[4]*w_;  acc[5]+=hp_[5]*w_;  acc[6]+=hp_[6]*w_;  acc[7]+=hp_[7]*w_; \
  acc[8]+=hp_[8]*w_;  acc[9]+=hp_[9]*w_;  acc[10]+=hp_[10]*w_; acc[11]+=hp_[11]*w_; \
  acc[12]+=hp_[12]*w_; acc[13]+=hp_[13]*w_; acc[14]+=hp_[14]*w_; acc[15]+=hp_[15]*w_; }

__global__ __launch_bounds__(256) void k_score(const float* __restrict__ W2,
    const float* __restrict__ b2, const float* __restrict__ g2, const float* __restrict__ lb2,
    const float* __restrict__ cw1, const float* __restrict__ cb1,
    const double* __restrict__ hT, const double* __restrict__ mu2, const double* __restrict__ isg,
    double* __restrict__ score, unsigned* __restrict__ key){
  int t = threadIdx.x;
  int p = blockIdx.x*256 + t;
  float4 w4[16];
  const float4* wp = (const float4*)(W2 + (size_t)p*64);
#pragma unroll
  for (int i=0;i<16;i++) w4[i] = wp[i];
  double g2p = (double)g2[p], lb2p = (double)lb2[p], b2p = (double)b2[p];
  double cb = (double)cb1[0];
  for (int b = 0; b < 4; b++){
    double acc[16];
#pragma unroll
    for (int j=0;j<16;j++) acc[j]=0.0;
    const double* hb = hT + b*16;   // uniform base
#pragma unroll
    for (int k4=0;k4<16;k4++){
      float4 wv = w4[k4];
      SC_K(wv.x, (k4*4+0))
      SC_K(wv.y, (k4*4+1))
      SC_K(wv.z, (k4*4+2))
      SC_K(wv.w, (k4*4+3))
    }
    double sc = cb;
#pragma unroll
    for (int j=0;j<16;j++){
      int c = b*16 + j;
      double tv = acc[j] + b2p;
      double z = (tv - mu2[c]) * isg[c];
      double v = z * g2p + lb2p;
      v = v > 0.0 ? v : 0.0;
      sc += v * (double)cw1[j];
    }
    if (sc == 0.0) sc = 0.0;   // canonicalize -0.0
    score[(size_t)b*HWN + p] = sc;
    key[(size_t)b*HWN + p] = monokey(sc);
  }
}

// ------------------------------------------------------------ radix top-K
__global__ void k_hist(const unsigned* __restrict__ key, const unsigned* __restrict__ state,
                       unsigned* __restrict__ hist, int pass){
  __shared__ unsigned lh[256];
  int t = threadIdx.x;
  int b = blockIdx.x >> 7, seg = blockIdx.x & 127;
  lh[t] = 0u;
  __syncthreads();
  unsigned pref = state[b*4+0];
  const unsigned* kb = key + (size_t)b*HWN + seg*2048;
  int shb = 24 - 8*pass;
#pragma unroll
  for (int i=0;i<8;i++){
    unsigned kk = kb[t + 256*i];
    bool ok = (pass == 0) || ((kk >> (32 - 8*pass)) == pref);
    if (ok) atomicAdd(&lh[(kk >> shb) & 255u], 1u);
  }
  __syncthreads();
  atomicAdd(&hist[(pass*4 + b)*256 + t], lh[t]);
}

__global__ void k_scan(unsigned* __restrict__ state, const unsigned* __restrict__ hist, int pass){
  __shared__ unsigned ls[4*256];
  int t = threadIdx.x;          // 1024
  int b = t >> 8, j = t & 255;
  unsigned cnt = hist[(pass*4 + b)*256 + j];
  int q = 255 - j;              // reversed position
  ls[b*256 + q] = cnt;
  __syncthreads();
  for (int o=1;o<256;o<<=1){
    unsigned v = (q >= o) ? ls[b*256 + q - o] : 0u;
    __syncthreads();
    ls[b*256 + q] += v;
    __syncthreads();
  }
  unsigned need = state[b*4+1];
  unsigned pref = state[b*4+0];
  unsigned GT = (j == 255) ? 0u : ls[b*256 + (254 - j)];
  unsigned GE = ls[b*256 + (255 - j)];
  if (GT < need && need <= GE){
    unsigned npref = (pref << 8) | (unsigned)j;
    state[b*4+0] = npref;
    state[b*4+1] = need - GT;
    if (pass == 3){ state[b*4+2] = npref; state[b*4+3] = need - GT; }
  }
}

__global__ __launch_bounds__(256) void k_mask(const unsigned* __restrict__ key,
    const unsigned* __restrict__ state, float* __restrict__ outM,
    unsigned* __restrict__ bcnt, unsigned* __restrict__ tiecnt, unsigned* __restrict__ tielist){
  __shared__ int red[256];
  int t = threadIdx.x;
  int b = blockIdx.x >> 8, seg = blockIdx.x & 255;
  unsigned T = state[b*4+2];
  int p0 = seg*1024 + t*4;
  size_t base = (size_t)b*HWN + p0;
  uint4 kk = *((const uint4*)(key + base));
  float4 mv; int cnt = 0;
  { int s = kk.x > T; mv.x = s ? 1.f : 0.f; cnt += s;
    if (kk.x == T){ unsigned ti = atomicAdd(&tiecnt[b],1u); if (ti < TIECAP) tielist[b*TIECAP+ti] = (unsigned)(p0+0); } }
  { int s = kk.y > T; mv.y = s ? 1.f : 0.f; cnt += s;
    if (kk.y == T){ unsigned ti = atomicAdd(&tiecnt[b],1u); if (ti < TIECAP) tielist[b*TIECAP+ti] = (unsigned)(p0+1); } }
  { int s = kk.z > T; mv.z = s ? 1.f : 0.f; cnt += s;
    if (kk.z == T){ unsigned ti = atomicAdd(&tiecnt[b],1u); if (ti < TIECAP) tielist[b*TIECAP+ti] = (unsigned)(p0+2); } }
  { int s = kk.w > T; mv.w = s ? 1.f : 0.f; cnt += s;
    if (kk.w == T){ unsigned ti = atomicAdd(&tiecnt[b],1u); if (ti < TIECAP) tielist[b*TIECAP+ti] = (unsigned)(p0+3); } }
  *((float4*)(outM + base)) = mv;
  red[t] = cnt;
  __syncthreads();
  for (int o=128;o>0;o>>=1){ if (t < o) red[t] += red[t+o]; __syncthreads(); }
  if (t == 0) bcnt[b*256 + seg] = (unsigned)red[0];
}

__global__ __launch_bounds__(256) void k_ties(const unsigned* __restrict__ state,
    const unsigned* __restrict__ tiecnt, const unsigned* __restrict__ tielist,
    const double* __restrict__ score, float* __restrict__ outM,
    unsigned* __restrict__ chcnt, unsigned* __restrict__ chlist){
  __shared__ double ssc[TIECAP];
  __shared__ unsigned spp[TIECAP];
  __shared__ unsigned skeep[TIECAP];
  int b = blockIdx.x, t = threadIdx.x;
  unsigned tc = tiecnt[b];
  int n = (int)(tc < (unsigned)TIECAP ? tc : (unsigned)TIECAP);
  unsigned nt = state[b*4+3];
  for (int i=t;i<n;i+=256){
    unsigned p = tielist[b*TIECAP+i];
    spp[i] = p; ssc[i] = score[(size_t)b*HWN + p];
  }
  __syncthreads();
  for (int i=t;i<n;i+=256){
    double si = ssc[i]; unsigned pi = spp[i]; int r = 0;
    for (int j=0;j<n;j++){
      double sj = ssc[j]; unsigned pj = spp[j];
      if (sj > si || (sj == si && pj < pi)) r++;
    }
    skeep[i] = (r < (int)nt) ? 1u : 0u;
  }
  __syncthreads();
  for (int i=t;i<n;i+=256){
    if (skeep[i]){
      unsigned pi = spp[i]; int r2 = 0;
      for (int j=0;j<n;j++) if (skeep[j] && spp[j] < pi) r2++;
      chlist[b*TIECAP + r2] = pi;
      outM[(size_t)b*HWN + pi] = 1.0f;
    }
  }
  if (t == 0){
    unsigned c = ((unsigned)n < nt) ? (unsigned)n : nt;
    chcnt[b] = c;
  }
}

__global__ void k_scanblk(const unsigned* __restrict__ bcnt, unsigned* __restrict__ boff){
  __shared__ unsigned ls[1024];
  int t = threadIdx.x; int b = t >> 8, j = t & 255;
  unsigned own = bcnt[b*256 + j];
  ls[t] = own;
  __syncthreads();
  for (int o=1;o<256;o<<=1){
    unsigned v = (j >= o) ? ls[b*256 + j - o] : 0u;
    __syncthreads();
    ls[t] += v;
    __syncthreads();
  }
  boff[b*256 + j] = ls[t] - own;
}

__device__ __forceinline__ void gath_one(unsigned kv, int p, unsigned T,
    const unsigned* __restrict__ cl, unsigned nch, unsigned base, int& run,
    const float* __restrict__ inp, float* __restrict__ g, int b){
  int isGT = kv > T;
  int isCh = 0;
  if (kv == T && nch > 0u){
    for (unsigned j=0;j<nch;j++) if (cl[j] == (unsigned)p){ isCh = 1; break; }
  }
  if (isGT | isCh){
    unsigned adj = 0;
    for (unsigned j=0;j<nch;j++) adj += (cl[j] < (unsigned)p) ? 1u : 0u;
    unsigned rank = base + (unsigned)run + adj;
#pragma unroll
    for (int c=0;c<16;c++)
      g[(size_t)(b*16+c)*KSEL + rank] = inp[(size_t)(b*16+c)*HWN + p];
  }
  run += isGT;
}

__global__ __launch_bounds__(256) void k_gather(const unsigned* __restrict__ key,
    const unsigned* __restrict__ state, const unsigned* __restrict__ boff,
    const unsigned* __restrict__ chcnt, const unsigned* __restrict__ chlist,
    const float* __restrict__ inp, float* __restrict__ g){
  __shared__ int wt[4];
  int t = threadIdx.x;
  int b = blockIdx.x >> 8, seg = blockIdx.x & 255;
  unsigned T = state[b*4+2];
  int p0 = seg*1024 + t*4;
  uint4 kk = *((const uint4*)(key + (size_t)b*HWN + p0));
  int s0 = kk.x > T, s1 = kk.y > T, s2 = kk.z > T, s3 = kk.w > T;
  int cnt = s0 + s1 + s2 + s3;
  int l = t & 63;
  int incl = cnt;
#pragma unroll
  for (int o=1;o<64;o<<=1){ int v = __shfl_up(incl, o); if (l >= o) incl += v; }
  int w = t >> 6;
  if (l == 63) wt[w] = incl;
  __syncthreads();
  int wex = 0;
#pragma unroll
  for (int i=0;i<4;i++) if (i < w) wex += wt[i];
  int exth = incl - cnt;
  unsigned base = boff[b*256 + seg] + (unsigned)wex + (unsigned)exth;
  unsigned nch = chcnt[b];
  const unsigned* cl = chlist + b*TIECAP;
  int run = 0;
  gath_one(kk.x, p0+0, T, cl, nch, base, run, inp, g, b);
  gath_one(kk.y, p0+1, T, cl, nch, base, run, inp, g, b);
  gath_one(kk.z, p0+2, T, cl, nch, base, run, inp, g, b);
  gath_one(kk.w, p0+3, T, cl, nch, base, run, inp, g, b);
}

// ------------------------------------------------------------- conv3x3 + stats
__global__ __launch_bounds__(256) void k_conv(const float* __restrict__ g,
    const float* __restrict__ cw3, const float* __restrict__ cb3,
    float* __restrict__ outY, double* __restrict__ bnp){
  __shared__ float wsm[2304];
  __shared__ float it[18*18];
  __shared__ double red[16][4][2];
  int t = threadIdx.x;
  int b = blockIdx.x >> 8, tile = blockIdx.x & 255;
  int ty0 = (tile >> 4) * 16, tx0 = (tile & 15) * 16;
  int tx = t & 15, ty = t >> 4;
#pragma unroll
  for (int i=0;i<9;i++){ int j = t + 256*i; if (j < 2304) wsm[j] = cw3[j]; }
  float acc[16];
#pragma unroll
  for (int i=0;i<16;i++) acc[i] = 0.f;
  for (int ic=0; ic<16; ic++){
    __syncthreads();
    for (int j=t;j<324;j+=256){
      int gy = ty0 - 1 + j/18, gx = tx0 - 1 + (j%18);
      float v = 0.f;
      if (gy >= 0 && gy < 256 && gx >= 0 && gx < 256)
        v = g[(size_t)(b*16+ic)*KSEL + gy*256 + gx];
      it[j] = v;
    }
    __syncthreads();
#pragma unroll
    for (int ky=0;ky<3;ky++)
#pragma unroll
      for (int kx=0;kx<3;kx++){
        float v = it[(ty+ky)*18 + tx+kx];
#pragma unroll
        for (int oc=0;oc<16;oc++) acc[oc] += v * wsm[oc*144 + ic*9 + ky*3 + kx];
      }
  }
  int w = t >> 6, l = t & 63;
  for (int oc=0;oc<16;oc++){
    float yv = acc[oc] + cb3[oc];
    outY[(size_t)(b*16+oc)*KSEL + (ty0+ty)*256 + tx0+tx] = yv;
    double s = (double)yv, q = (double)yv*(double)yv;
    for (int o=32;o>0;o>>=1){ s += __shfl_down(s, o); q += __shfl_down(q, o); }
    if (l == 0){ red[oc][w][0] = s; red[oc][w][1] = q; }
  }
  __syncthreads();
  if (t < 16){
    double s=0.0, q=0.0;
    for (int w2=0;w2<4;w2++){ s += red[t][w2][0]; q += red[t][w2][1]; }
    bnp[(size_t)blockIdx.x*32 + t*2]   = s;
    bnp[(size_t)blockIdx.x*32 + t*2+1] = q;
  }
}

__global__ void k_bnred(const double* __restrict__ bnp, const float* __restrict__ bng,
                        const float* __restrict__ bnb, float* __restrict__ bnc){
  __shared__ double red[16][16][2];
  int t = threadIdx.x; int oc = t >> 4, sl = t & 15;
  double s = 0.0, q = 0.0;
  for (int i=0;i<64;i++){
    int blk = sl*64 + i;
    s += bnp[(size_t)blk*32 + oc*2];
    q += bnp[(size_t)blk*32 + oc*2+1];
  }
  red[oc][sl][0] = s; red[oc][sl][1] = q;
  __syncthreads();
  if (t < 16){
    double S=0.0, Q=0.0;
    for (int i=0;i<16;i++){ S += red[t][i][0]; Q += red[t][i][1]; }
    double N = 262144.0;
    double mu = S/N, var = Q/N - mu*mu;
    double inv = 1.0 / sqrt(var + 1e-5);
    double a = (double)bng[t] * inv;
    double bsh = (double)bnb[t] - mu*a;
    bnc[t*2] = (float)a; bnc[t*2+1] = (float)bsh;
  }
}

__global__ void k_bnapply(float* __restrict__ outY, const float* __restrict__ bnc){
  int i = blockIdx.x*256 + threadIdx.x;   // float4 index, total 1048576
  float4 v = ((float4*)outY)[i];
  int oc = (i >> 14) & 15;
  float a = bnc[oc*2], bsh = bnc[oc*2+1];
  v.x = fmaxf(v.x*a + bsh, 0.f);
  v.y = fmaxf(v.y*a + bsh, 0.f);
  v.z = fmaxf(v.z*a + bsh, 0.f);
  v.w = fmaxf(v.w*a + bsh, 0.f);
  ((float4*)outY)[i] = v;
}

// =============================================================== launch
extern "C" void kernel_launch(void* const* d_in, const int* in_sizes, int n_in,
                              void* d_out, int out_size, void* d_ws, size_t ws_size,
                              hipStream_t stream){
  const float* inp  = (const float*)d_in[0];
  const float* W1   = (const float*)d_in[1];
  const float* b1   = (const float*)d_in[2];
  const float* g1   = (const float*)d_in[3];
  const float* b1l  = (const float*)d_in[4];
  const float* W2   = (const float*)d_in[5];
  const float* b2   = (const float*)d_in[6];
  const float* g2   = (const float*)d_in[7];
  const float* lb2  = (const float*)d_in[8];
  const float* cw1  = (const float*)d_in[9];
  const float* cb1  = (const float*)d_in[10];
  const float* cw3  = (const float*)d_in[11];
  const float* cb3  = (const float*)d_in[12];
  const float* bng  = (const float*)d_in[13];
  const float* bnb  = (const float*)d_in[14];
  (void)in_sizes; (void)n_in; (void)out_size;

  char* ws = (char*)d_ws;
  float* outY = (float*)d_out;
  float* outM = outY + 4194304;

  // partG [NBH][4226] + partD [NBH][4096] live only during k_mm..reductions;
  // score/key (12.58 MB) and gbuf (16.78 MB at +12.58 MB) reuse the region after.
  size_t need512  = (size_t)REGION2 + 512ull*4352*8 + 16777216ull;    // known-passing probe
  int NBH = (ws_size >= need512) ? 512 : 128;
  int pPerBlk = HWN / NBH;
  int bPerGrp = NBH / 16;

  double*  partG  = (double*)(ws + REGION2);
  double*  partD  = (double*)(ws + REGION2 + (size_t)NBH*PS_GRAM*8);
  double*  score  = (double*)(ws + REGION2);
  unsigned* key   = (unsigned*)(ws + REGION2 + 8388608ull);
  float*   gbuf   = (float*)(ws + REGION2 + 12582912ull);
  double*  hbuf   = (double*)(ws + OFF_H);
  double*  hTbuf  = (double*)(ws + OFF_HT);
  double*  dot1   = (double*)(ws + OFF_DOT1);
  double*  G      = (double*)(ws + OFF_G);
  double*  wbar   = (double*)(ws + OFF_WBAR);
  double*  wb     = (double*)(ws + OFF_WB);
  double*  sbv    = (double*)(ws + OFF_SB);
  double*  mu2    = (double*)(ws + OFF_MU2);
  double*  isg    = (double*)(ws + OFF_ISIG2);
  unsigned* state = (unsigned*)(ws + OFF_STATE);
  unsigned* hist  = (unsigned*)(ws + OFF_HIST);
  unsigned* tiecnt= (unsigned*)(ws + OFF_TIECNT);
  unsigned* chcnt = (unsigned*)(ws + OFF_CHCNT);
  unsigned* tielist=(unsigned*)(ws + OFF_TIELST);
  unsigned* chlist= (unsigned*)(ws + OFF_CHLST);
  unsigned* bcnt  = (unsigned*)(ws + OFF_BCNT);
  unsigned* boff  = (unsigned*)(ws + OFF_BOFF);
  double*  bnp    = (double*)(ws + OFF_BNP);
  float*   bnc    = (float*)(ws + OFF_BNC);
  double*  part2  = (double*)(ws + OFF_PART2);

  k_zero<<<1, 256, 0, stream>>>(hist, tiecnt, chcnt, state);
  k_mm<<<2*NBH, 256, 0, stream>>>(W2, b2, inp, W1, partG, partD, pPerBlk, NBH);
  k_red1<<<17*16, 256, 0, stream>>>(partG, part2, bPerGrp, PS_GRAM);
  k_redgram2<<<17, 256, 0, stream>>>(part2, G, wb, wbar, sbv);
  k_red1<<<16*16, 256, 0, stream>>>(partD, part2, bPerGrp, PS_DOT);
  k_reddot2<<<16, 256, 0, stream>>>(part2, dot1);
  k_h<<<1, 64, 0, stream>>>(dot1, b1, g1, b1l, wbar, sbv, hbuf, hTbuf, mu2);
  k_var2<<<64, 64, 0, stream>>>(hbuf, G, wb, sbv, mu2, isg);
  k_score<<<1024, 256, 0, stream>>>(W2, b2, g2, lb2, cw1, cb1, hTbuf, mu2, isg, score, key);
  for (int pass = 0; pass < 4; pass++){
    k_hist<<<512, 256, 0, stream>>>(key, state, hist, pass);
    k_scan<<<1, 1024, 0, stream>>>(state, hist, pass);
  }
  k_mask<<<1024, 256, 0, stream>>>(key, state, outM, bcnt, tiecnt, tielist);
  k_ties<<<4, 256, 0, stream>>>(state, tiecnt, tielist, score, outM, chcnt, chlist);
  k_scanblk<<<1, 1024, 0, stream>>>(bcnt, boff);
  k_gather<<<1024, 256, 0, stream>>>(key, state, boff, chcnt, chlist, inp, gbuf);
  k_conv<<<1024, 256, 0, stream>>>(gbuf, cw3, cb3, outY, bnp);
  k_bnred<<<1, 256, 0, stream>>>(bnp, bng, bnb, bnc);
  k_bnapply<<<4096, 256, 0, stream>>>(outY, bnc);
}

// Round 11
// 375.875 us; speedup vs baseline: 1.0432x; 1.0432x over previous
//
#include <hip/hip_runtime.h>

#define HWN    262144
#define KSEL   65536
#define TIECAP 2048

// ---- small-region byte offsets in d_ws
#define OFF_H      0          // double[64*64]   h (post LN1+relu), row-major
#define OFF_DOT1   32768      // double[64*64]   reduced GEMM1
#define OFF_G      65536      // double[64*64]   W2^T W2
#define OFF_WBAR   98304      // double[64]      col sums of W2
#define OFF_WB     98816      // double[64]      sum W2[:,k]*b2
#define OFF_SB     99328      // double[2]       {sum b2, sum b2^2}
#define OFF_MU2    99360      // double[64]
#define OFF_ISIG2  99872      // double[64]
#define OFF_STATE  100384     // u32[4][4] {prefix, need, T, needT}
#define OFF_HIST   100448     // u32[4 passes][4][256]
#define OFF_TIECNT 116832     // u32[4]
#define OFF_CHCNT  116848     // u32[4]
#define OFF_TIELST 116864     // u32[4][TIECAP]
#define OFF_CHLST  149632     // u32[4][TIECAP]
#define OFF_BCNT   182400     // u32[4][256]
#define OFF_BOFF   186496     // u32[4][256]
#define OFF_BNP    190592     // double[1024][16][2]
#define OFF_BNC    452736     // float[16][2]
#define OFF_PART2  458752     // double[16][4226] stage-1 reduction output (540928 B)
#define OFF_HT     1015808    // double[64 k][64 row] h transposed (32768 B)
#define REGION2    1048576    // big region: partG|partD, later score/key/gbuf

#define PS_GRAM 4226          // [64][66] + {sb2, sb}
#define PS_DOT  4096          // [64][64]

typedef double d4_t __attribute__((ext_vector_type(4)));
typedef float  f4v  __attribute__((ext_vector_type(4)));

__device__ __forceinline__ unsigned monokey(double s){
  unsigned long long b = (unsigned long long)__double_as_longlong(s);
  b = (b & 0x8000000000000000ULL) ? ~b : (b | 0x8000000000000000ULL);
  return (unsigned)(b >> 32);
}

// ------------------------------------------------------------------ zero/init
__global__ void k_zero(unsigned* hist, unsigned* tiecnt, unsigned* chcnt, unsigned* state){
  int t = threadIdx.x;
  for (int i = t; i < 4096; i += 256) hist[i] = 0u;
  if (t < 4){
    tiecnt[t] = 0u; chcnt[t] = 0u;
    state[t*4+0] = 0u;          // prefix
    state[t*4+1] = (unsigned)KSEL; // need
    state[t*4+2] = 0u;          // T
    state[t*4+3] = 0u;          // needT
  }
}

// store one 16x16 MFMA tile (ai,bi) of the symmetric-gram layout.
// bi<4: full G tile; bi==4,ai<4: wb/wbar cols; ai==4: sb2/sb scalars.
__device__ __forceinline__ void st_tile(double* __restrict__ P, const d4_t& acc,
                                        const int* ri_, const int* ci_, int ai, int bi){
#pragma unroll
  for (int i = 0; i < 4; i++){
    int ri = ri_[i], ci = ci_[i];
    if (bi < 4)            P[(ai*16+ri)*66 + bi*16 + ci] = acc[i];
    else if (ai < 4){ if (ci < 2) P[(ai*16+ri)*66 + 64 + ci] = acc[i]; }
    else { if (ri == 0 && ci < 2) P[4224 + ci] = acc[i]; }  // [0][0]=sb2,[0][1]=sb
  }
}

// one gram K-step: upper-tri tiles spread 4/4/4/3 across waves
#define GRAM_STEP(F0,F1,F2,F3,FB) { \
  double f0=(double)(F0), f1=(double)(F1), f2=(double)(F2), f3=(double)(F3); \
  double f4=(m==0)?(double)(FB):((m==1)?1.0:0.0); \
  if (w == 0){ \
    accA = __builtin_amdgcn_mfma_f64_16x16x4f64(f0, f0, accA, 0, 0, 0); \
    accB = __builtin_amdgcn_mfma_f64_16x16x4f64(f0, f1, accB, 0, 0, 0); \
    accC = __builtin_amdgcn_mfma_f64_16x16x4f64(f0, f2, accC, 0, 0, 0); \
    accD = __builtin_amdgcn_mfma_f64_16x16x4f64(f0, f3, accD, 0, 0, 0); \
  } else if (w == 1){ \
    accA = __builtin_amdgcn_mfma_f64_16x16x4f64(f1, f1, accA, 0, 0, 0); \
    accB = __builtin_amdgcn_mfma_f64_16x16x4f64(f1, f2, accB, 0, 0, 0); \
    accC = __builtin_amdgcn_mfma_f64_16x16x4f64(f1, f3, accC, 0, 0, 0); \
    accD = __builtin_amdgcn_mfma_f64_16x16x4f64(f1, f4, accD, 0, 0, 0); \
  } else if (w == 2){ \
    accA = __builtin_amdgcn_mfma_f64_16x16x4f64(f2, f2, accA, 0, 0, 0); \
    accB = __builtin_amdgcn_mfma_f64_16x16x4f64(f2, f3, accB, 0, 0, 0); \
    accC = __builtin_amdgcn_mfma_f64_16x16x4f64(f2, f4, accC, 0, 0, 0); \
    accD = __builtin_amdgcn_mfma_f64_16x16x4f64(f3, f4, accD, 0, 0, 0); \
  } else { \
    accA = __builtin_amdgcn_mfma_f64_16x16x4f64(f3, f3, accA, 0, 0, 0); \
    accB = __builtin_amdgcn_mfma_f64_16x16x4f64(f0, f4, accB, 0, 0, 0); \
    accC = __builtin_amdgcn_mfma_f64_16x16x4f64(f4, f4, accC, 0, 0, 0); \
  } }

// one gemm1 K-step (16 MFMAs from one register set)
#define G1_STEP(AV,B0,B1,B2,B3) { \
  _Pragma("unroll") \
  for (int t4 = 0; t4 < 4; t4++){ \
    double a = (double)(AV)[t4]; \
    acc0 = __builtin_amdgcn_mfma_f64_16x16x4f64(a, (double)(B0)[t4], acc0, 0, 0, 0); \
    acc1 = __builtin_amdgcn_mfma_f64_16x16x4f64(a, (double)(B1)[t4], acc1, 0, 0, 0); \
    acc2 = __builtin_amdgcn_mfma_f64_16x16x4f64(a, (double)(B2)[t4], acc2, 0, 0, 0); \
    acc3 = __builtin_amdgcn_mfma_f64_16x16x4f64(a, (double)(B3)[t4], acc3, 0, 0, 0); \
  } }

// ---------------- fused fp64-MFMA GEMMs: gram(W2) on blocks [0,NBH), GEMM1 on
// [NBH,2NBH).  Probe-store (verified R6) decodes the HW D-fragment (row,col).
// R11: ping-pong 2x unroll — R10's rolled rotation cost ~20 v_mov per 16 MFMA
// (VALUBusy 46%); two named register sets eliminate the movs entirely.
__global__ __launch_bounds__(256) void k_mm(const float* __restrict__ W2,
                                            const float* __restrict__ b2,
                                            const float* __restrict__ inp,
                                            const float* __restrict__ W1,
                                            double* __restrict__ partG,
                                            double* __restrict__ partD,
                                            int pPerBlk, int NBH){
  int t = threadIdx.x;
  int w = t >> 6, l = t & 63;
  int q = l >> 4, m = l & 15;
  if ((int)blockIdx.x < NBH){
    // ---------------- gram path: Atilde = [W2 | b2 | 1], upper-tri tiles only
    int p0 = blockIdx.x * pPerBlk;
    d4_t accA = {0.,0.,0.,0.}, accB = {0.,0.,0.,0.};
    d4_t accC = {0.,0.,0.,0.}, accD = {0.,0.,0.,0.};
    const float* base = W2 + (size_t)(p0 + q)*64 + m;
    const float* b2p  = b2 + p0 + q;
    int nPair = pPerBlk >> 3;       // chunks of 4 p, two per pair (nCh even)
    float gA0 = base[0], gA1 = base[16], gA2 = base[32], gA3 = base[48];
    float gAb = b2p[0];
    for (int i = 0; i < nPair; i++){
      float gB0 = base[256+0], gB1 = base[256+16], gB2 = base[256+32], gB3 = base[256+48];
      float gBb = b2p[4];
      GRAM_STEP(gA0, gA1, gA2, gA3, gAb)
      base += 512; b2p += 8;
      if (i + 1 < nPair){
        gA0 = base[0]; gA1 = base[16]; gA2 = base[32]; gA3 = base[48];
        gAb = b2p[0];
      }
      GRAM_STEP(gB0, gB1, gB2, gB3, gBb)
    }
    // probes: prD = 4*(1+row), pcD = 4*(1+col) under the HW's true maps
    d4_t prD = {0.,0.,0.,0.}, pcD = {0.,0.,0.,0.};
    double rp = (double)(1 + m);
    prD = __builtin_amdgcn_mfma_f64_16x16x4f64(rp, 1.0, prD, 0, 0, 0);
    pcD = __builtin_amdgcn_mfma_f64_16x16x4f64(1.0, rp, pcD, 0, 0, 0);
    int ri_[4], ci_[4];
#pragma unroll
    for (int i = 0; i < 4; i++){
      ri_[i] = ((((int)prD[i]) >> 2) - 1) & 15;
      ci_[i] = ((((int)pcD[i]) >> 2) - 1) & 15;
    }
    double* P = partG + (size_t)blockIdx.x * PS_GRAM;
    if (w == 0){
      st_tile(P, accA, ri_, ci_, 0, 0); st_tile(P, accB, ri_, ci_, 0, 1);
      st_tile(P, accC, ri_, ci_, 0, 2); st_tile(P, accD, ri_, ci_, 0, 3);
    } else if (w == 1){
      st_tile(P, accA, ri_, ci_, 1, 1); st_tile(P, accB, ri_, ci_, 1, 2);
      st_tile(P, accC, ri_, ci_, 1, 3); st_tile(P, accD, ri_, ci_, 1, 4);
    } else if (w == 2){
      st_tile(P, accA, ri_, ci_, 2, 2); st_tile(P, accB, ri_, ci_, 2, 3);
      st_tile(P, accC, ri_, ci_, 2, 4); st_tile(P, accD, ri_, ci_, 3, 4);
    } else {
      st_tile(P, accA, ri_, ci_, 3, 3); st_tile(P, accB, ri_, ci_, 0, 4);
      st_tile(P, accC, ri_, ci_, 4, 4);
    }
  } else {
    // ---------------- GEMM1 path: dot1[r][k] = sum_p inp[r][p] * W1[k][p]
    int blk = (int)blockIdx.x - NBH;
    int p0 = blk * pPerBlk;
    d4_t acc0 = {0.,0.,0.,0.}, acc1 = {0.,0.,0.,0.};
    d4_t acc2 = {0.,0.,0.,0.}, acc3 = {0.,0.,0.,0.};
    const f4v* ap  = (const f4v*)(inp + (size_t)(w*16 + m)*HWN + p0 + q*4);
    const f4v* bp0 = (const f4v*)(W1  + (size_t)( 0 + m)*HWN + p0 + q*4);
    const f4v* bp1 = (const f4v*)(W1  + (size_t)(16 + m)*HWN + p0 + q*4);
    const f4v* bp2 = (const f4v*)(W1  + (size_t)(32 + m)*HWN + p0 + q*4);
    const f4v* bp3 = (const f4v*)(W1  + (size_t)(48 + m)*HWN + p0 + q*4);
    int nPair = pPerBlk >> 5;       // chunks of 16 p, two per pair (nCh even)
    f4v avA = ap[0], b0A = bp0[0], b1A = bp1[0], b2A = bp2[0], b3A = bp3[0];
    for (int i = 0; i < nPair; i++){
      size_t x1 = (size_t)(2*i+1)*4;
      f4v avB = ap[x1], b0B = bp0[x1], b1B = bp1[x1], b2B = bp2[x1], b3B = bp3[x1];
      G1_STEP(avA, b0A, b1A, b2A, b3A)
      if (i + 1 < nPair){
        size_t x2 = (size_t)(2*i+2)*4;
        avA = ap[x2]; b0A = bp0[x2]; b1A = bp1[x2]; b2A = bp2[x2]; b3A = bp3[x2];
      }
      G1_STEP(avB, b0B, b1B, b2B, b3B)
    }
    d4_t prD = {0.,0.,0.,0.}, pcD = {0.,0.,0.,0.};
    double rp = (double)(1 + m);
    prD = __builtin_amdgcn_mfma_f64_16x16x4f64(rp, 1.0, prD, 0, 0, 0);
    pcD = __builtin_amdgcn_mfma_f64_16x16x4f64(1.0, rp, pcD, 0, 0, 0);
    double* P = partD + (size_t)blk * PS_DOT;
#pragma unroll
    for (int i = 0; i < 4; i++){
      int ri = ((((int)prD[i]) >> 2) - 1) & 15;
      int ci = ((((int)pcD[i]) >> 2) - 1) & 15;
      int r = w*16 + ri;
      P[r*64 +  0 + ci] = acc0[i];
      P[r*64 + 16 + ci] = acc1[i];
      P[r*64 + 32 + ci] = acc2[i];
      P[r*64 + 48 + ci] = acc3[i];
    }
  }
}

// ------------------------------------------------- two-stage partial reduction
// Stage 1: [NBH][cnt] -> [16][cnt].  Grid = ceil(cnt/256) j-chunks * 16 groups.
__global__ __launch_bounds__(256) void k_red1(const double* __restrict__ part,
                                              double* __restrict__ part2,
                                              int bPerGrp, int cnt){
  int nj = (cnt + 255) >> 8;
  int jc = blockIdx.x % nj;
  int grp = blockIdx.x / nj;
  int j = jc*256 + threadIdx.x;
  if (j >= cnt) return;
  const double* p = part + (size_t)grp * bPerGrp * cnt + j;
  double s0=0.0, s1=0.0, s2=0.0, s3=0.0;
  for (int b = 0; b < bPerGrp; b += 4){
    s0 += p[(size_t)(b+0)*cnt];
    s1 += p[(size_t)(b+1)*cnt];
    s2 += p[(size_t)(b+2)*cnt];
    s3 += p[(size_t)(b+3)*cnt];
  }
  part2[(size_t)grp*cnt + j] = (s0+s1) + (s2+s3);
}

// Stage 2 (gram): [16][4226] -> G/wb/wbar/sbv.  Lower-triangle blocks mirror
// from the transposed stored tile (k_mm writes upper-tri tiles only).
__global__ void k_redgram2(const double* __restrict__ part2,
                           double* __restrict__ G, double* __restrict__ wb,
                           double* __restrict__ wbar, double* __restrict__ sbv){
  int j = blockIdx.x*256 + threadIdx.x;
  if (j >= PS_GRAM) return;
  int src = j;
  int r = 0, c = 0;
  if (j < 4224){
    r = j / 66; c = j % 66;
    if (c < 64){
      int rb = r >> 4, cb = c >> 4;
      if (cb < rb)  // lower block: value lives in tile (cb, rb) transposed
        src = ((cb*16 + (c & 15)) * 66) + rb*16 + (r & 15);
    }
  }
  double s = 0.0;
#pragma unroll
  for (int b = 0; b < 16; b++) s += part2[(size_t)b*PS_GRAM + src];
  if (j < 4224){
    if (c < 64) G[r*64 + c] = s;
    else if (c == 64) wb[r] = s;
    else wbar[r] = s;
  } else if (j == 4224) sbv[1] = s;   // sum b2^2
  else sbv[0] = s;                    // sum b2
}

// Stage 2 (dot1): [16][4096] -> dot1[4096]
__global__ void k_reddot2(const double* __restrict__ part2, double* __restrict__ dot1){
  int j = blockIdx.x*256 + threadIdx.x;
  if (j >= PS_DOT) return;
  double s = 0.0;
#pragma unroll
  for (int b = 0; b < 16; b++) s += part2[(size_t)b*PS_DOT + j];
  dot1[j] = s;
}

// ------------------- LN1 -> h (row-major + transposed), and LN2 mean (analytic)
__global__ void k_h(const double* __restrict__ dot1, const float* __restrict__ b1,
                    const float* __restrict__ g1, const float* __restrict__ b1l,
                    const double* __restrict__ wbar, const double* __restrict__ sbv,
                    double* __restrict__ h, double* __restrict__ hT,
                    double* __restrict__ mu2){
  int r = threadIdx.x; // 0..63
  double m = 0.0;
  for (int k=0;k<64;k++) m += dot1[r*64+k] + (double)b1[k];
  m *= (1.0/64.0);
  double v = 0.0;
  for (int k=0;k<64;k++){ double d = dot1[r*64+k] + (double)b1[k] - m; v += d*d; }
  v *= (1.0/64.0);
  double inv = 1.0 / sqrt(v + 1e-5);
  double s2 = 0.0;
  for (int k=0;k<64;k++){
    double x = dot1[r*64+k] + (double)b1[k];
    double z = (x - m) * inv;
    double hv = z * (double)g1[k] + (double)b1l[k];
    hv = hv > 0.0 ? hv : 0.0;
    h[r*64+k] = hv;
    hT[k*64+r] = hv;
    s2 += hv * wbar[k];
  }
  mu2[r] = (s2 + sbv[0]) / (double)HWN;
}

// -------------------------------------------------- LN2 variance via Gram(W2)
__global__ void k_var2(const double* __restrict__ h, const double* __restrict__ G,
                       const double* __restrict__ wb, const double* __restrict__ sbv,
                       const double* __restrict__ mu2, double* __restrict__ isig2){
  int r = blockIdx.x, k = threadIdx.x;
  double hk = h[r*64+k];
  double v = 0.0;
  for (int l=0;l<64;l++) v += G[k*64+l] * h[r*64+l];
  double contrib = hk*v + 2.0*hk*wb[k];
  for (int o=32;o>0;o>>=1) contrib += __shfl_down(contrib, o);
  if (k == 0){
    double E2 = (contrib + sbv[1]) / (double)HWN;
    double mu = mu2[r];
    double var = E2 - mu*mu;
    isig2[r] = 1.0 / sqrt(var + 1e-5);
  }
}

// ------------------------------------------------ GEMM2 + LN2 + relu + score
// hT rows are wave-uniform -> scalar (s_load) broadcast, no LDS at all.
#define SC_K(WF, KIDX) { \
  double w_ = (double)(WF); \
  const double* hp_ = hb + (KIDX)*64; \
  acc[0]+=hp_[0]*w_;  acc[1]+=hp_[1]*w_;  acc[2]+=hp_[2]*w_;  acc[3]+=hp_[3]*w_; \
  acc[4]+=hp_[4]*w_;  acc[5]+=hp_[5]*w_;  acc[6]+=hp_[6]*w_;  acc[7]+=hp_[7]*w_; \
  acc[8]+=hp_[8]*w_;  acc[9]+=hp_[9]*w_;  acc[10]+=hp_[10]*w_; acc[11]+=hp_[11]*w_; \
  acc[12]+=hp_[12]*w_; acc[13]+=hp_[13]*w_; acc[14]+=hp_[14]*w_; acc[15]+=hp_[15]*w_; }

__global__ __launch_bounds__(256) void k_score(const float* __restrict__ W2,
    const float* __restrict__ b2, const float* __restrict__ g2, const float* __restrict__ lb2,
    const float* __restrict__ cw1, const float* __restrict__ cb1,
    const double* __restrict__ hT, const double* __restrict__ mu2, const double* __restrict__ isg,
    double* __restrict__ score, unsigned* __restrict__ key){
  int t = threadIdx.x;
  int p = blockIdx.x*256 + t;
  float4 w4[16];
  const float4* wp = (const float4*)(W2 + (size_t)p*64);
#pragma unroll
  for (int i=0;i<16;i++) w4[i] = wp[i];
  double g2p = (double)g2[p], lb2p = (double)lb2[p], b2p = (double)b2[p];
  double cb = (double)cb1[0];
  for (int b = 0; b < 4; b++){
    double acc[16];
#pragma unroll
    for (int j=0;j<16;j++) acc[j]=0.0;
    const double* hb = hT + b*16;   // uniform base
#pragma unroll
    for (int k4=0;k4<16;k4++){
      float4 wv = w4[k4];
      SC_K(wv.x, (k4*4+0))
      SC_K(wv.y, (k4*4+1))
      SC_K(wv.z, (k4*4+2))
      SC_K(wv.w, (k4*4+3))
    }
    double sc = cb;
#pragma unroll
    for (int j=0;j<16;j++){
      int c = b*16 + j;
      double tv = acc[j] + b2p;
      double z = (tv - mu2[c]) * isg[c];
      double v = z * g2p + lb2p;
      v = v > 0.0 ? v : 0.0;
      sc += v * (double)cw1[j];
    }
    if (sc == 0.0) sc = 0.0;   // canonicalize -0.0
    score[(size_t)b*HWN + p] = sc;
    key[(size_t)b*HWN + p] = monokey(sc);
  }
}

// ------------------------------------------------------------ radix top-K
__global__ void k_hist(const unsigned* __restrict__ key, const unsigned* __restrict__ state,
                       unsigned* __restrict__ hist, int pass){
  __shared__ unsigned lh[256];
  int t = threadIdx.x;
  int b = blockIdx.x >> 7, seg = blockIdx.x & 127;
  lh[t] = 0u;
  __syncthreads();
  unsigned pref = state[b*4+0];
  const unsigned* kb = key + (size_t)b*HWN + seg*2048;
  int shb = 24 - 8*pass;
#pragma unroll
  for (int i=0;i<8;i++){
    unsigned kk = kb[t + 256*i];
    bool ok = (pass == 0) || ((kk >> (32 - 8*pass)) == pref);
    if (ok) atomicAdd(&lh[(kk >> shb) & 255u], 1u);
  }
  __syncthreads();
  atomicAdd(&hist[(pass*4 + b)*256 + t], lh[t]);
}

__global__ void k_scan(unsigned* __restrict__ state, const unsigned* __restrict__ hist, int pass){
  __shared__ unsigned ls[4*256];
  int t = threadIdx.x;          // 1024
  int b = t >> 8, j = t & 255;
  unsigned cnt = hist[(pass*4 + b)*256 + j];
  int q = 255 - j;              // reversed position
  ls[b*256 + q] = cnt;
  __syncthreads();
  for (int o=1;o<256;o<<=1){
    unsigned v = (q >= o) ? ls[b*256 + q - o] : 0u;
    __syncthreads();
    ls[b*256 + q] += v;
    __syncthreads();
  }
  unsigned need = state[b*4+1];
  unsigned pref = state[b*4+0];
  unsigned GT = (j == 255) ? 0u : ls[b*256 + (254 - j)];
  unsigned GE = ls[b*256 + (255 - j)];
  if (GT < need && need <= GE){
    unsigned npref = (pref << 8) | (unsigned)j;
    state[b*4+0] = npref;
    state[b*4+1] = need - GT;
    if (pass == 3){ state[b*4+2] = npref; state[b*4+3] = need - GT; }
  }
}

__global__ __launch_bounds__(256) void k_mask(const unsigned* __restrict__ key,
    const unsigned* __restrict__ state, float* __restrict__ outM,
    unsigned* __restrict__ bcnt, unsigned* __restrict__ tiecnt, unsigned* __restrict__ tielist){
  __shared__ int red[256];
  int t = threadIdx.x;
  int b = blockIdx.x >> 8, seg = blockIdx.x & 255;
  unsigned T = state[b*4+2];
  int p0 = seg*1024 + t*4;
  size_t base = (size_t)b*HWN + p0;
  uint4 kk = *((const uint4*)(key + base));
  float4 mv; int cnt = 0;
  { int s = kk.x > T; mv.x = s ? 1.f : 0.f; cnt += s;
    if (kk.x == T){ unsigned ti = atomicAdd(&tiecnt[b],1u); if (ti < TIECAP) tielist[b*TIECAP+ti] = (unsigned)(p0+0); } }
  { int s = kk.y > T; mv.y = s ? 1.f : 0.f; cnt += s;
    if (kk.y == T){ unsigned ti = atomicAdd(&tiecnt[b],1u); if (ti < TIECAP) tielist[b*TIECAP+ti] = (unsigned)(p0+1); } }
  { int s = kk.z > T; mv.z = s ? 1.f : 0.f; cnt += s;
    if (kk.z == T){ unsigned ti = atomicAdd(&tiecnt[b],1u); if (ti < TIECAP) tielist[b*TIECAP+ti] = (unsigned)(p0+2); } }
  { int s = kk.w > T; mv.w = s ? 1.f : 0.f; cnt += s;
    if (kk.w == T){ unsigned ti = atomicAdd(&tiecnt[b],1u); if (ti < TIECAP) tielist[b*TIECAP+ti] = (unsigned)(p0+3); } }
  *((float4*)(outM + base)) = mv;
  red[t] = cnt;
  __syncthreads();
  for (int o=128;o>0;o>>=1){ if (t < o) red[t] += red[t+o]; __syncthreads(); }
  if (t == 0) bcnt[b*256 + seg] = (unsigned)red[0];
}

__global__ __launch_bounds__(256) void k_ties(const unsigned* __restrict__ state,
    const unsigned* __restrict__ tiecnt, const unsigned* __restrict__ tielist,
    const double* __restrict__ score, float* __restrict__ outM,
    unsigned* __restrict__ chcnt, unsigned* __restrict__ chlist){
  __shared__ double ssc[TIECAP];
  __shared__ unsigned spp[TIECAP];
  __shared__ unsigned skeep[TIECAP];
  int b = blockIdx.x, t = threadIdx.x;
  unsigned tc = tiecnt[b];
  int n = (int)(tc < (unsigned)TIECAP ? tc : (unsigned)TIECAP);
  unsigned nt = state[b*4+3];
  for (int i=t;i<n;i+=256){
    unsigned p = tielist[b*TIECAP+i];
    spp[i] = p; ssc[i] = score[(size_t)b*HWN + p];
  }
  __syncthreads();
  for (int i=t;i<n;i+=256){
    double si = ssc[i]; unsigned pi = spp[i]; int r = 0;
    for (int j=0;j<n;j++){
      double sj = ssc[j]; unsigned pj = spp[j];
      if (sj > si || (sj == si && pj < pi)) r++;
    }
    skeep[i] = (r < (int)nt) ? 1u : 0u;
  }
  __syncthreads();
  for (int i=t;i<n;i+=256){
    if (skeep[i]){
      unsigned pi = spp[i]; int r2 = 0;
      for (int j=0;j<n;j++) if (skeep[j] && spp[j] < pi) r2++;
      chlist[b*TIECAP + r2] = pi;
      outM[(size_t)b*HWN + pi] = 1.0f;
    }
  }
  if (t == 0){
    unsigned c = ((unsigned)n < nt) ? (unsigned)n : nt;
    chcnt[b] = c;
  }
}

__global__ void k_scanblk(const unsigned* __restrict__ bcnt, unsigned* __restrict__ boff){
  __shared__ unsigned ls[1024];
  int t = threadIdx.x; int b = t >> 8, j = t & 255;
  unsigned own = bcnt[b*256 + j];
  ls[t] = own;
  __syncthreads();
  for (int o=1;o<256;o<<=1){
    unsigned v = (j >= o) ? ls[b*256 + j - o] : 0u;
    __syncthreads();
    ls[t] += v;
    __syncthreads();
  }
  boff[b*256 + j] = ls[t] - own;
}

__device__ __forceinline__ void gath_one(unsigned kv, int p, unsigned T,
    const unsigned* __restrict__ cl, unsigned nch, unsigned base, int& run,
    const float* __restrict__ inp, float* __restrict__ g, int b){
  int isGT = kv > T;
  int isCh = 0;
  if (kv == T && nch > 0u){
    for (unsigned j=0;j<nch;j++) if (cl[j] == (unsigned)p){ isCh = 1; break; }
  }
  if (isGT | isCh){
    unsigned adj = 0;
    for (unsigned j=0;j<nch;j++) adj += (cl[j] < (unsigned)p) ? 1u : 0u;
    unsigned rank = base + (unsigned)run + adj;
#pragma unroll
    for (int c=0;c<16;c++)
      g[(size_t)(b*16+c)*KSEL + rank] = inp[(size_t)(b*16+c)*HWN + p];
  }
  run += isGT;
}

__global__ __launch_bounds__(256) void k_gather(const unsigned* __restrict__ key,
    const unsigned* __restrict__ state, const unsigned* __restrict__ boff,
    const unsigned* __restrict__ chcnt, const unsigned* __restrict__ chlist,
    const float* __restrict__ inp, float* __restrict__ g){
  __shared__ int wt[4];
  int t = threadIdx.x;
  int b = blockIdx.x >> 8, seg = blockIdx.x & 255;
  unsigned T = state[b*4+2];
  int p0 = seg*1024 + t*4;
  uint4 kk = *((const uint4*)(key + (size_t)b*HWN + p0));
  int s0 = kk.x > T, s1 = kk.y > T, s2 = kk.z > T, s3 = kk.w > T;
  int cnt = s0 + s1 + s2 + s3;
  int l = t & 63;
  int incl = cnt;
#pragma unroll
  for (int o=1;o<64;o<<=1){ int v = __shfl_up(incl, o); if (l >= o) incl += v; }
  int w = t >> 6;
  if (l == 63) wt[w] = incl;
  __syncthreads();
  int wex = 0;
#pragma unroll
  for (int i=0;i<4;i++) if (i < w) wex += wt[i];
  int exth = incl - cnt;
  unsigned base = boff[b*256 + seg] + (unsigned)wex + (unsigned)exth;
  unsigned nch = chcnt[b];
  const unsigned* cl = chlist + b*TIECAP;
  int run = 0;
  gath_one(kk.x, p0+0, T, cl, nch, base, run, inp, g, b);
  gath_one(kk.y, p0+1, T, cl, nch, base, run, inp, g, b);
  gath_one(kk.z, p0+2, T, cl, nch, base, run, inp, g, b);
  gath_one(kk.w, p0+3, T, cl, nch, base, run, inp, g, b);
}

// ------------------------------------------------------------- conv3x3 + stats
__global__ __launch_bounds__(256) void k_conv(const float* __restrict__ g,
    const float* __restrict__ cw3, const float* __restrict__ cb3,
    float* __restrict__ outY, double* __restrict__ bnp){
  __shared__ float wsm[2304];
  __shared__ float it[18*18];
  __shared__ double red[16][4][2];
  int t = threadIdx.x;
  int b = blockIdx.x >> 8, tile = blockIdx.x & 255;
  int ty0 = (tile >> 4) * 16, tx0 = (tile & 15) * 16;
  int tx = t & 15, ty = t >> 4;
#pragma unroll
  for (int i=0;i<9;i++){ int j = t + 256*i; if (j < 2304) wsm[j] = cw3[j]; }
  float acc[16];
#pragma unroll
  for (int i=0;i<16;i++) acc[i] = 0.f;
  for (int ic=0; ic<16; ic++){
    __syncthreads();
    for (int j=t;j<324;j+=256){
      int gy = ty0 - 1 + j/18, gx = tx0 - 1 + (j%18);
      float v = 0.f;
      if (gy >= 0 && gy < 256 && gx >= 0 && gx < 256)
        v = g[(size_t)(b*16+ic)*KSEL + gy*256 + gx];
      it[j] = v;
    }
    __syncthreads();
#pragma unroll
    for (int ky=0;ky<3;ky++)
#pragma unroll
      for (int kx=0;kx<3;kx++){
        float v = it[(ty+ky)*18 + tx+kx];
#pragma unroll
        for (int oc=0;oc<16;oc++) acc[oc] += v * wsm[oc*144 + ic*9 + ky*3 + kx];
      }
  }
  int w = t >> 6, l = t & 63;
  for (int oc=0;oc<16;oc++){
    float yv = acc[oc] + cb3[oc];
    outY[(size_t)(b*16+oc)*KSEL + (ty0+ty)*256 + tx0+tx] = yv;
    double s = (double)yv, q = (double)yv*(double)yv;
    for (int o=32;o>0;o>>=1){ s += __shfl_down(s, o); q += __shfl_down(q, o); }
    if (l == 0){ red[oc][w][0] = s; red[oc][w][1] = q; }
  }
  __syncthreads();
  if (t < 16){
    double s=0.0, q=0.0;
    for (int w2=0;w2<4;w2++){ s += red[t][w2][0]; q += red[t][w2][1]; }
    bnp[(size_t)blockIdx.x*32 + t*2]   = s;
    bnp[(size_t)blockIdx.x*32 + t*2+1] = q;
  }
}

__global__ void k_bnred(const double* __restrict__ bnp, const float* __restrict__ bng,
                        const float* __restrict__ bnb, float* __restrict__ bnc){
  __shared__ double red[16][16][2];
  int t = threadIdx.x; int oc = t >> 4, sl = t & 15;
  double s = 0.0, q = 0.0;
  for (int i=0;i<64;i++){
    int blk = sl*64 + i;
    s += bnp[(size_t)blk*32 + oc*2];
    q += bnp[(size_t)blk*32 + oc*2+1];
  }
  red[oc][sl][0] = s; red[oc][sl][1] = q;
  __syncthreads();
  if (t < 16){
    double S=0.0, Q=0.0;
    for (int i=0;i<16;i++){ S += red[t][i][0]; Q += red[t][i][1]; }
    double N = 262144.0;
    double mu = S/N, var = Q/N - mu*mu;
    double inv = 1.0 / sqrt(var + 1e-5);
    double a = (double)bng[t] * inv;
    double bsh = (double)bnb[t] - mu*a;
    bnc[t*2] = (float)a; bnc[t*2+1] = (float)bsh;
  }
}

__global__ void k_bnapply(float* __restrict__ outY, const float* __restrict__ bnc){
  int i = blockIdx.x*256 + threadIdx.x;   // float4 index, total 1048576
  float4 v = ((float4*)outY)[i];
  int oc = (i >> 14) & 15;
  float a = bnc[oc*2], bsh = bnc[oc*2+1];
  v.x = fmaxf(v.x*a + bsh, 0.f);
  v.y = fmaxf(v.y*a + bsh, 0.f);
  v.z = fmaxf(v.z*a + bsh, 0.f);
  v.w = fmaxf(v.w*a + bsh, 0.f);
  ((float4*)outY)[i] = v;
}

// =============================================================== launch
extern "C" void kernel_launch(void* const* d_in, const int* in_sizes, int n_in,
                              void* d_out, int out_size, void* d_ws, size_t ws_size,
                              hipStream_t stream){
  const float* inp  = (const float*)d_in[0];
  const float* W1   = (const float*)d_in[1];
  const float* b1   = (const float*)d_in[2];
  const float* g1   = (const float*)d_in[3];
  const float* b1l  = (const float*)d_in[4];
  const float* W2   = (const float*)d_in[5];
  const float* b2   = (const float*)d_in[6];
  const float* g2   = (const float*)d_in[7];
  const float* lb2  = (const float*)d_in[8];
  const float* cw1  = (const float*)d_in[9];
  const float* cb1  = (const float*)d_in[10];
  const float* cw3  = (const float*)d_in[11];
  const float* cb3  = (const float*)d_in[12];
  const float* bng  = (const float*)d_in[13];
  const float* bnb  = (const float*)d_in[14];
  (void)in_sizes; (void)n_in; (void)out_size;

  char* ws = (char*)d_ws;
  float* outY = (float*)d_out;
  float* outM = outY + 4194304;

  // partG [NBH][4226] + partD [NBH][4096] live only during k_mm..reductions;
  // score/key (12.58 MB) and gbuf (16.78 MB at +12.58 MB) reuse the region after.
  size_t need512  = (size_t)REGION2 + 512ull*4352*8 + 16777216ull;    // known-passing probe
  int NBH = (ws_size >= need512) ? 512 : 128;
  int pPerBlk = HWN / NBH;
  int bPerGrp = NBH / 16;

  double*  partG  = (double*)(ws + REGION2);
  double*  partD  = (double*)(ws + REGION2 + (size_t)NBH*PS_GRAM*8);
  double*  score  = (double*)(ws + REGION2);
  unsigned* key   = (unsigned*)(ws + REGION2 + 8388608ull);
  float*   gbuf   = (float*)(ws + REGION2 + 12582912ull);
  double*  hbuf   = (double*)(ws + OFF_H);
  double*  hTbuf  = (double*)(ws + OFF_HT);
  double*  dot1   = (double*)(ws + OFF_DOT1);
  double*  G      = (double*)(ws + OFF_G);
  double*  wbar   = (double*)(ws + OFF_WBAR);
  double*  wb     = (double*)(ws + OFF_WB);
  double*  sbv    = (double*)(ws + OFF_SB);
  double*  mu2    = (double*)(ws + OFF_MU2);
  double*  isg    = (double*)(ws + OFF_ISIG2);
  unsigned* state = (unsigned*)(ws + OFF_STATE);
  unsigned* hist  = (unsigned*)(ws + OFF_HIST);
  unsigned* tiecnt= (unsigned*)(ws + OFF_TIECNT);
  unsigned* chcnt = (unsigned*)(ws + OFF_CHCNT);
  unsigned* tielist=(unsigned*)(ws + OFF_TIELST);
  unsigned* chlist= (unsigned*)(ws + OFF_CHLST);
  unsigned* bcnt  = (unsigned*)(ws + OFF_BCNT);
  unsigned* boff  = (unsigned*)(ws + OFF_BOFF);
  double*  bnp    = (double*)(ws + OFF_BNP);
  float*   bnc    = (float*)(ws + OFF_BNC);
  double*  part2  = (double*)(ws + OFF_PART2);

  k_zero<<<1, 256, 0, stream>>>(hist, tiecnt, chcnt, state);
  k_mm<<<2*NBH, 256, 0, stream>>>(W2, b2, inp, W1, partG, partD, pPerBlk, NBH);
  k_red1<<<17*16, 256, 0, stream>>>(partG, part2, bPerGrp, PS_GRAM);
  k_redgram2<<<17, 256, 0, stream>>>(part2, G, wb, wbar, sbv);
  k_red1<<<16*16, 256, 0, stream>>>(partD, part2, bPerGrp, PS_DOT);
  k_reddot2<<<16, 256, 0, stream>>>(part2, dot1);
  k_h<<<1, 64, 0, stream>>>(dot1, b1, g1, b1l, wbar, sbv, hbuf, hTbuf, mu2);
  k_var2<<<64, 64, 0, stream>>>(hbuf, G, wb, sbv, mu2, isg);
  k_score<<<1024, 256, 0, stream>>>(W2, b2, g2, lb2, cw1, cb1, hTbuf, mu2, isg, score, key);
  for (int pass = 0; pass < 4; pass++){
    k_hist<<<512, 256, 0, stream>>>(key, state, hist, pass);
    k_scan<<<1, 1024, 0, stream>>>(state, hist, pass);
  }
  k_mask<<<1024, 256, 0, stream>>>(key, state, outM, bcnt, tiecnt, tielist);
  k_ties<<<4, 256, 0, stream>>>(state, tiecnt, tielist, score, outM, chcnt, chlist);
  k_scanblk<<<1, 1024, 0, stream>>>(bcnt, boff);
  k_gather<<<1024, 256, 0, stream>>>(key, state, boff, chcnt, chlist, inp, gbuf);
  k_conv<<<1024, 256, 0, stream>>>(gbuf, cw3, cb3, outY, bnp);
  k_bnred<<<1, 256, 0, stream>>>(bnp, bng, bnb, bnc);
  k_bnapply<<<4096, 256, 0, stream>>>(outY, bnc);
}